// Round 2
// baseline (1843.009 us; speedup 1.0000x reference)
//
#include <hip/hip_runtime.h>
#include <math.h>

#define N 8192
#define D 256
#define TM 32     // rows per block
#define TN 128    // cols per j-tile
#define KC 64     // K chunk
#define SA 68     // LDS row stride (floats) for A chunk [TM][KC]  (68%32=4 -> bank spread; 68*4%16==0 -> float4 aligned)
#define SB 68     // LDS row stride for B chunk [TN][KC]
#define EPSF 1e-8f

// ws layout (floats):
//   [0,N)        sq       (= kinetic)
//   [N,2N)       norm
//   [2N,3N)      rinv     (1/max(norm,1e-12))
//   [3N,4N)      deg
//   [4N,5N)      pot      (sum_j adj*G; potential = -pot)
//   [5N,6N)      ent
//   [6N,6N+256)  gmean
//   [6N+256]     maxnorm (float bits, atomicMax as uint)
//   [6N+512, +5N ints)  nbr indices
//   [11N+512, +65536)   column partial sums
// total ~625 KB

__global__ void k_rowstats(const float* __restrict__ emb, float* __restrict__ ws) {
    int row = blockIdx.x * 4 + (threadIdx.x >> 6);
    int lane = threadIdx.x & 63;
    float4 v = *(const float4*)(emb + (size_t)row * D + lane * 4);
    float s = v.x * v.x + v.y * v.y + v.z * v.z + v.w * v.w;
#pragma unroll
    for (int mk = 32; mk >= 1; mk >>= 1) s += __shfl_xor(s, mk);
    if (lane == 0) {
        ws[row] = s;
        float nrm = sqrtf(s);
        ws[N + row] = nrm;
        ws[2 * N + row] = 1.0f / fmaxf(nrm, 1e-12f);
        atomicMax((unsigned*)(ws + 6 * N + 256), __float_as_uint(nrm));
    }
}

__global__ void k_colpart(const float* __restrict__ emb, float* __restrict__ part) {
    int d = threadIdx.x;
    int b = blockIdx.x;
    float s = 0.f;
    for (int r = b * 32; r < b * 32 + 32; ++r) s += emb[(size_t)r * D + d];
    part[b * 256 + d] = s;
}

__global__ void k_colred(const float* __restrict__ part, float* __restrict__ gmean) {
    int d = threadIdx.x;
    float s = 0.f;
    for (int b = 0; b < 256; ++b) s += part[b * 256 + d];
    gmean[d] = s * (1.0f / N);
}

__global__ __launch_bounds__(256) void k_main(const float* __restrict__ emb,
                                              const float* __restrict__ adj,
                                              float* __restrict__ ws,
                                              int* __restrict__ nbr) {
    __shared__ float smem[TM * SA + TN * SB];  // 2176 + 8704 floats = 43520 B
    float* As = smem;
    float* Bs = smem + TM * SA;

    const int tid = threadIdx.x;
    const int tx = tid & 31;   // col group: cols c = tx + 32*i
    const int ty = tid >> 5;   // row group: rows r = ty*4 + dr
    const int row0 = blockIdx.x * TM;

    float sq_i[4], rv_i[4];
#pragma unroll
    for (int dr = 0; dr < 4; ++dr) {
        int r = row0 + ty * 4 + dr;
        sq_i[dr] = ws[r];
        rv_i[dr] = ws[2 * N + r];
    }

    float deg[4] = {0.f, 0.f, 0.f, 0.f};
    float pot[4] = {0.f, 0.f, 0.f, 0.f};
    float sm_m[4], sm_l[4] = {0.f, 0.f, 0.f, 0.f}, sm_t[4] = {0.f, 0.f, 0.f, 0.f};
#pragma unroll
    for (int dr = 0; dr < 4; ++dr) sm_m[dr] = -1e30f;
    float tv[4][5];
    int tix[4][5];
#pragma unroll
    for (int dr = 0; dr < 4; ++dr)
#pragma unroll
        for (int s = 0; s < 5; ++s) { tv[dr][s] = 1e30f; tix[dr][s] = N; }

    for (int jt = 0; jt < N / TN; ++jt) {
        const int j0 = jt * TN;

        // prefetch per-tile operands early (adj is the HBM stream; hide under GEMM)
        float sq_j[4], rv_j[4], adjv[4][4];
#pragma unroll
        for (int i = 0; i < 4; ++i) {
            int j = j0 + tx + 32 * i;
            sq_j[i] = ws[j];
            rv_j[i] = ws[2 * N + j];
        }
#pragma unroll
        for (int dr = 0; dr < 4; ++dr) {
            size_t rbase = (size_t)(row0 + ty * 4 + dr) * N + j0;
#pragma unroll
            for (int i = 0; i < 4; ++i) adjv[dr][i] = adj[rbase + tx + 32 * i];
        }

        float acc[4][4];
#pragma unroll
        for (int dr = 0; dr < 4; ++dr)
#pragma unroll
            for (int i = 0; i < 4; ++i) acc[dr][i] = 0.f;

        for (int kh = 0; kh < D / KC; ++kh) {
            const int k0 = kh * KC;
            // stage A chunk [TM][KC] (row-major, padded)
#pragma unroll
            for (int q = 0; q < 2; ++q) {
                int e4 = tid + q * 256;
                int r = e4 >> 4, kk4 = e4 & 15;
                float4 v = *(const float4*)(emb + (size_t)(row0 + r) * D + k0 + kk4 * 4);
                *(float4*)(As + r * SA + kk4 * 4) = v;
            }
            // stage B chunk [TN][KC]
#pragma unroll
            for (int q = 0; q < 8; ++q) {
                int e4 = tid + q * 256;
                int c = e4 >> 4, kk4 = e4 & 15;
                float4 v = *(const float4*)(emb + (size_t)(j0 + c) * D + k0 + kk4 * 4);
                *(float4*)(Bs + c * SB + kk4 * 4) = v;
            }
            __syncthreads();
#pragma unroll
            for (int kq = 0; kq < KC; kq += 4) {
                float4 a[4], b[4];
#pragma unroll
                for (int dr = 0; dr < 4; ++dr) a[dr] = *(const float4*)(As + (ty * 4 + dr) * SA + kq);
#pragma unroll
                for (int i = 0; i < 4; ++i) b[i] = *(const float4*)(Bs + (tx + 32 * i) * SB + kq);
#pragma unroll
                for (int dr = 0; dr < 4; ++dr)
#pragma unroll
                    for (int i = 0; i < 4; ++i) {
                        acc[dr][i] = fmaf(a[dr].x, b[i].x, acc[dr][i]);
                        acc[dr][i] = fmaf(a[dr].y, b[i].y, acc[dr][i]);
                        acc[dr][i] = fmaf(a[dr].z, b[i].z, acc[dr][i]);
                        acc[dr][i] = fmaf(a[dr].w, b[i].w, acc[dr][i]);
                    }
            }
            __syncthreads();
        }

        // epilogue: fold this tile's G values into per-row state
#pragma unroll
        for (int dr = 0; dr < 4; ++dr) {
            const int grow = row0 + ty * 4 + dr;
#pragma unroll
            for (int i = 0; i < 4; ++i) {
                const float g = acc[dr][i];
                const int j = j0 + tx + 32 * i;
                const float av = adjv[dr][i];
                deg[dr] += av;
                pot[dr] = fmaf(av, g, pot[dr]);
                // online softmax over masked logits
                const float s = g * rv_i[dr] * rv_j[i] * av;
                const float nm = fmaxf(sm_m[dr], s);
                const float sc = __expf(sm_m[dr] - nm);
                const float e = __expf(s - nm);
                sm_l[dr] = fmaf(sm_l[dr], sc, e);
                sm_t[dr] = fmaf(sm_t[dr], sc, e * s);
                sm_m[dr] = nm;
                // top-5 nearest (exclude self), branchless sorted insert
                float d2 = sq_i[dr] + sq_j[i] - 2.0f * g;
                d2 = (j == grow) ? 1e30f : d2;
                const bool b4 = d2 < tv[dr][4];
                const bool b3 = d2 < tv[dr][3];
                const bool b2 = d2 < tv[dr][2];
                const bool b1 = d2 < tv[dr][1];
                const bool b0 = d2 < tv[dr][0];
                tv[dr][4] = b4 ? (b3 ? tv[dr][3] : d2) : tv[dr][4];
                tix[dr][4] = b4 ? (b3 ? tix[dr][3] : j) : tix[dr][4];
                tv[dr][3] = b3 ? (b2 ? tv[dr][2] : d2) : tv[dr][3];
                tix[dr][3] = b3 ? (b2 ? tix[dr][2] : j) : tix[dr][3];
                tv[dr][2] = b2 ? (b1 ? tv[dr][1] : d2) : tv[dr][2];
                tix[dr][2] = b2 ? (b1 ? tix[dr][1] : j) : tix[dr][2];
                tv[dr][1] = b1 ? (b0 ? tv[dr][0] : d2) : tv[dr][1];
                tix[dr][1] = b1 ? (b0 ? tix[dr][0] : j) : tix[dr][1];
                tv[dr][0] = b0 ? d2 : tv[dr][0];
                tix[dr][0] = b0 ? j : tix[dr][0];
            }
        }
    }

    // cross-lane merges: 32 tx-lanes share each row (contiguous within a wave half)
#pragma unroll
    for (int dr = 0; dr < 4; ++dr) {
        float m_ = sm_m[dr], l_ = sm_l[dr], t_ = sm_t[dr], d_ = deg[dr], p_ = pot[dr];
#pragma unroll
        for (int mk = 16; mk >= 1; mk >>= 1) {
            d_ += __shfl_xor(d_, mk);
            p_ += __shfl_xor(p_, mk);
            float mo = __shfl_xor(m_, mk);
            float lo = __shfl_xor(l_, mk);
            float to = __shfl_xor(t_, mk);
            float nm = fmaxf(m_, mo);
            float s1 = __expf(m_ - nm), s2 = __expf(mo - nm);
            l_ = l_ * s1 + lo * s2;
            t_ = t_ * s1 + to * s2;
            m_ = nm;
        }
        if (tx == 0) {
            int r = row0 + ty * 4 + dr;
            ws[3 * N + r] = d_;
            ws[4 * N + r] = p_;
            ws[5 * N + r] = m_ + logf(l_) - t_ / l_;
        }
    }

    // top-5 merge across the 32 tx lists per row, via LDS
    __syncthreads();
#pragma unroll
    for (int dr = 0; dr < 4; ++dr) {
        int r = ty * 4 + dr;
#pragma unroll
        for (int s = 0; s < 5; ++s) {
            int base = ((r * 32 + tx) * 5 + s) * 2;
            smem[base] = tv[dr][s];
            smem[base + 1] = __int_as_float(tix[dr][s]);
        }
    }
    __syncthreads();
    if (tid < 32) {
        const int r = tid;
#pragma unroll 1
        for (int sel = 0; sel < 5; ++sel) {
            float best = 1e30f;
            int bi = 1 << 29, bq = 0;
            for (int q = 0; q < 160; ++q) {
                float d = smem[(r * 160 + q) * 2];
                int ix = __float_as_int(smem[(r * 160 + q) * 2 + 1]);
                if (d < best || (d == best && ix < bi)) { best = d; bi = ix; bq = q; }
            }
            smem[(r * 160 + bq) * 2] = 1e30f;  // remove picked
            nbr[(row0 + r) * 5 + sel] = bi;
        }
    }
}

__global__ void k_final(const float* __restrict__ emb, const float* __restrict__ ws,
                        const int* __restrict__ nbr, float* __restrict__ out) {
    int row = blockIdx.x * 4 + (threadIdx.x >> 6);
    int lane = threadIdx.x & 63;
    float4 e = *(const float4*)(emb + (size_t)row * D + lane * 4);
    float4 gm = *(const float4*)(ws + 6 * N + lane * 4);
    float gx = e.x - gm.x, gy = e.y - gm.y, gz = e.z - gm.z, gw = e.w - gm.w;
    float gd = gx * gx + gy * gy + gz * gz + gw * gw;
    float ax = 0.f, ay = 0.f, az = 0.f, aw = 0.f;
#pragma unroll
    for (int t = 0; t < 5; ++t) {
        int ix = nbr[row * 5 + t];
        float4 nv = *(const float4*)(emb + (size_t)ix * D + lane * 4);
        ax += nv.x; ay += nv.y; az += nv.z; aw += nv.w;
    }
    ax *= 0.2f; ay *= 0.2f; az *= 0.2f; aw *= 0.2f;
    float lx = e.x - ax, ly = e.y - ay, lz = e.z - az, lw = e.w - aw;
    float ld = lx * lx + ly * ly + lz * lz + lw * lw;
#pragma unroll
    for (int mk = 32; mk >= 1; mk >>= 1) {
        gd += __shfl_xor(gd, mk);
        ld += __shfl_xor(ld, mk);
    }
    if (lane == 0) {
        float sq = ws[row], nrm = ws[N + row];
        float degv = ws[3 * N + row], potv = ws[4 * N + row], entv = ws[5 * N + row];
        float mn = ws[6 * N + 256];  // float bits written via atomicMax(uint)
        out[row] = sq - potv / (degv + EPSF);
        out[N + row] = (degv > 0.f) ? entv : 0.f;
        out[2 * N + row] = 0.6f * sqrtf(gd) + 0.4f * sqrtf(ld);
        out[3 * N + row] = 0.5f * (degv / (8191.0f + EPSF)) + 0.5f * (nrm / (mn + EPSF));
    }
}

extern "C" void kernel_launch(void* const* d_in, const int* in_sizes, int n_in,
                              void* d_out, int out_size, void* d_ws, size_t ws_size,
                              hipStream_t stream) {
    const float* emb = (const float*)d_in[0];
    const float* adj = (const float*)d_in[1];
    float* out = (float*)d_out;
    float* ws = (float*)d_ws;
    int* nbr = (int*)(ws + 6 * N + 512);
    float* part = ws + 11 * N + 512;

    hipMemsetAsync(ws + 6 * N + 256, 0, 4, stream);  // maxnorm
    k_rowstats<<<N / 4, 256, 0, stream>>>(emb, ws);
    k_colpart<<<256, 256, 0, stream>>>(emb, part);
    k_colred<<<1, 256, 0, stream>>>(part, ws + 6 * N);
    k_main<<<N / TM, 256, 0, stream>>>(emb, adj, ws, nbr);
    k_final<<<N / 4, 256, 0, stream>>>(emb, ws, nbr, out);
}

// Round 4
// 324.251 us; speedup vs baseline: 5.6839x; 5.6839x over previous
//
#include <hip/hip_runtime.h>
#include <math.h>

#define N 8192
#define D 256
#define EPSF 1e-8f

// ws layout (floats):
#define WS_SQ    0                      // [N]  |x_r|^2 (fp32 exact)
#define WS_RINV  (N)                    // [N]  1/max(||x_r||,1e-12)
#define WS_GMEAN (2*N)                  // [256]
#define WS_MAXN  (2*N+256)              // [1] max norm (uint-ordered float)
#define WS_COLP  (2*N+512)              // [65536] column partial sums
#define WS_PDEG  (2*N+512+65536)        // [4N] per-jsplit deg
// pout relative offsets (base = WS_PDEG): pot +4N, l +8N, t +12N, tv +16N (20N)
#define WS_TIX   (WS_PDEG+36*N)         // [20N] ints: per-jsplit top5 indices
#define WS_EBF   (WS_PDEG+56*N)         // [2M ushort] bf16 emb copy (4MB)
// total ~6.1 MB

typedef __attribute__((ext_vector_type(8))) short bf16x8;
typedef __attribute__((ext_vector_type(4))) float f32x4;

__device__ __forceinline__ unsigned short f2bf(float f) {
    unsigned u = __float_as_uint(f);
    u += 0x7fffu + ((u >> 16) & 1u);   // round-to-nearest-even
    return (unsigned short)(u >> 16);
}

// branchless sorted top-5 insert (ascending), gated on beating the current 5th
#define INS5(TV, TI, dpv, jv) do {                                              \
    if ((dpv) < (TV)[4]) {                                                      \
      bool _b3 = (dpv) < (TV)[3], _b2 = (dpv) < (TV)[2];                        \
      bool _b1 = (dpv) < (TV)[1], _b0 = (dpv) < (TV)[0];                        \
      (TV)[4] = _b3 ? (TV)[3] : (dpv); (TI)[4] = _b3 ? (TI)[3] : (jv);          \
      (TV)[3] = _b3 ? (_b2 ? (TV)[2] : (dpv)) : (TV)[3];                        \
      (TI)[3] = _b3 ? (_b2 ? (TI)[2] : (jv))  : (TI)[3];                        \
      (TV)[2] = _b2 ? (_b1 ? (TV)[1] : (dpv)) : (TV)[2];                        \
      (TI)[2] = _b2 ? (_b1 ? (TI)[1] : (jv))  : (TI)[2];                        \
      (TV)[1] = _b1 ? (_b0 ? (TV)[0] : (dpv)) : (TV)[1];                        \
      (TI)[1] = _b1 ? (_b0 ? (TI)[0] : (jv))  : (TI)[1];                        \
      (TV)[0] = _b0 ? (dpv) : (TV)[0]; (TI)[0] = _b0 ? (jv) : (TI)[0];          \
    }                                                                           \
  } while (0)

__global__ void k_prep(const float* __restrict__ emb, float* __restrict__ ws,
                       unsigned short* __restrict__ ebf) {
    int row = blockIdx.x * 4 + (threadIdx.x >> 6);
    int lane = threadIdx.x & 63;
    float4 v = *(const float4*)(emb + (size_t)row * D + lane * 4);
    ushort4 b;
    b.x = f2bf(v.x); b.y = f2bf(v.y); b.z = f2bf(v.z); b.w = f2bf(v.w);
    *(ushort4*)(ebf + (size_t)row * D + lane * 4) = b;
    float s = v.x * v.x + v.y * v.y + v.z * v.z + v.w * v.w;
#pragma unroll
    for (int mk = 32; mk >= 1; mk >>= 1) s += __shfl_xor(s, mk);
    if (lane == 0) {
        ws[WS_SQ + row] = s;
        float nrm = sqrtf(s);
        ws[WS_RINV + row] = 1.0f / fmaxf(nrm, 1e-12f);
        atomicMax((unsigned*)(ws + WS_MAXN), __float_as_uint(nrm));
    }
}

__global__ void k_colpart(const float* __restrict__ emb, float* __restrict__ part) {
    int d = threadIdx.x;
    int b = blockIdx.x;
    float s = 0.f;
    for (int r = b * 32; r < b * 32 + 32; ++r) s += emb[(size_t)r * D + d];
    part[b * 256 + d] = s;
}

__global__ void k_colred(const float* __restrict__ part, float* __restrict__ gmean) {
    int d = threadIdx.x;
    float s = 0.f;
    for (int b = 0; b < 256; ++b) s += part[b * 256 + d];
    gmean[d] = s * (1.0f / N);
}

// Main: MFMA Gram with swapped operands. Block = 4 waves, 32 output rows, one
// j-split (2048 cols). Wave w owns j in [jbase+w*512, +512), chunks of 64.
// No LDS / barriers in the main loop; final merge via LDS once.
__global__ __launch_bounds__(256, 2) void k_main(
    const float* __restrict__ adj,
    const unsigned short* __restrict__ ebf,
    const float* __restrict__ ws,
    float* __restrict__ pout,
    int* __restrict__ tixp)
{
    __shared__ float lds_s[4][32][4];
    __shared__ float lds_tv[4][32][5];
    __shared__ int   lds_ti[4][32][5];

    const int tid = threadIdx.x;
    const int w = tid >> 6;
    const int lane = tid & 63;
    const int lid = lane & 15;   // MFMA: n-index (output row), m-frag row index
    const int g = lane >> 4;     // MFMA: k-group; D m-index base = g*4
    const int panel = blockIdx.x >> 2;
    const int js = blockIdx.x & 3;
    const int row0 = panel * 32;
    const int jbase = js * 2048 + w * 512;

    const float* sq = ws + WS_SQ;
    const float* rinv = ws + WS_RINV;

    // persistent B-fragments: the block's 32 output rows, full K=256
    bf16x8 bfr[2][8];
    float rvr[2];
    int r_[2];
#pragma unroll
    for (int nf = 0; nf < 2; ++nf) {
        int r = row0 + nf * 16 + lid;
        r_[nf] = r;
        rvr[nf] = rinv[r];
#pragma unroll
        for (int ks = 0; ks < 8; ++ks)
            bfr[nf][ks] = *(const bf16x8*)(ebf + (size_t)r * D + ks * 32 + g * 8);
    }

    float deg[2] = {0.f, 0.f}, pot[2] = {0.f, 0.f};
    float sl[2] = {0.f, 0.f}, st[2] = {0.f, 0.f};
    float tv[2][5]; int tix[2][5];
#pragma unroll
    for (int nf = 0; nf < 2; ++nf)
#pragma unroll
        for (int s2 = 0; s2 < 5; ++s2) { tv[nf][s2] = 1e30f; tix[nf][s2] = N; }

#pragma unroll 1
    for (int c = 0; c < 8; ++c) {
        const int jw = jbase + c * 64;
        f32x4 acc[2][4];
#pragma unroll
        for (int nf = 0; nf < 2; ++nf)
#pragma unroll
            for (int mf = 0; mf < 4; ++mf) acc[nf][mf] = (f32x4){0.f, 0.f, 0.f, 0.f};

#pragma unroll
        for (int ks = 0; ks < 8; ++ks) {
            bf16x8 afr[4];
#pragma unroll
            for (int mf = 0; mf < 4; ++mf)
                afr[mf] = *(const bf16x8*)(ebf + (size_t)(jw + mf * 16 + lid) * D + ks * 32 + g * 8);
#pragma unroll
            for (int nf = 0; nf < 2; ++nf)
#pragma unroll
                for (int mf = 0; mf < 4; ++mf)
                    acc[nf][mf] = __builtin_amdgcn_mfma_f32_16x16x32_bf16(
                        afr[mf], bfr[nf][ks], acc[nf][mf], 0, 0, 0);
        }

        // epilogue operands: j-side stats (broadcast loads) + adj stream (nt)
        f32x4 sqv[4], rvv[4];
#pragma unroll
        for (int mf = 0; mf < 4; ++mf) {
            sqv[mf] = *(const f32x4*)(sq + jw + mf * 16 + g * 4);
            rvv[mf] = *(const f32x4*)(rinv + jw + mf * 16 + g * 4);
        }
#pragma unroll
        for (int nf = 0; nf < 2; ++nf) {
            const float* arow = adj + (size_t)r_[nf] * N + jw + g * 4;
            f32x4 adv[4];
#pragma unroll
            for (int mf = 0; mf < 4; ++mf)
                adv[mf] = __builtin_nontemporal_load((const f32x4*)(arow + mf * 16));
#pragma unroll
            for (int mf = 0; mf < 4; ++mf) {
#pragma unroll
                for (int e = 0; e < 4; ++e) {
                    const float gv = acc[nf][mf][e];     // G[r_[nf]][j]
                    const float a = adv[mf][e];
                    const int j = jw + mf * 16 + g * 4 + e;
                    deg[nf] += a;
                    pot[nf] = fmaf(a, gv, pot[nf]);
                    const float s = gv * rvr[nf] * rvv[mf][e] * a;  // masked cosine, |s|<=~1
                    const float ex = __expf(s);
                    sl[nf] += ex;
                    st[nf] = fmaf(ex, s, st[nf]);
                    float dp = fmaf(-2.f, gv, sqv[mf][e]);  // d2 - sq_r (row-const dropped)
                    dp = (j == r_[nf]) ? 1e30f : dp;
                    INS5(tv[nf], tix[nf], dp, j);
                }
            }
        }
    }

    // cross-g reduce (lanes l, l^16, l^32, l^48 share an output row)
#pragma unroll
    for (int nf = 0; nf < 2; ++nf) {
#pragma unroll
        for (int mk = 16; mk <= 32; mk <<= 1) {
            deg[nf] += __shfl_xor(deg[nf], mk);
            pot[nf] += __shfl_xor(pot[nf], mk);
            sl[nf] += __shfl_xor(sl[nf], mk);
            st[nf] += __shfl_xor(st[nf], mk);
            float od[5]; int oi[5];
#pragma unroll
            for (int s2 = 0; s2 < 5; ++s2) {
                od[s2] = __shfl_xor(tv[nf][s2], mk);
                oi[s2] = __shfl_xor(tix[nf][s2], mk);
            }
#pragma unroll
            for (int s2 = 0; s2 < 5; ++s2) INS5(tv[nf], tix[nf], od[s2], oi[s2]);
        }
        if (g == 0) {
            int lr = nf * 16 + lid;
            lds_s[w][lr][0] = deg[nf]; lds_s[w][lr][1] = pot[nf];
            lds_s[w][lr][2] = sl[nf];  lds_s[w][lr][3] = st[nf];
#pragma unroll
            for (int s2 = 0; s2 < 5; ++s2) {
                lds_tv[w][lr][s2] = tv[nf][s2];
                lds_ti[w][lr][s2] = tix[nf][s2];
            }
        }
    }
    __syncthreads();

    // cross-wave merge + partial write (one thread per row)
    if (tid < 32) {
        float dg = 0.f, pt = 0.f, ll = 0.f, tt = 0.f;
#pragma unroll
        for (int w2 = 0; w2 < 4; ++w2) {
            dg += lds_s[w2][tid][0]; pt += lds_s[w2][tid][1];
            ll += lds_s[w2][tid][2]; tt += lds_s[w2][tid][3];
        }
        float mtv[5]; int mti[5];
#pragma unroll
        for (int s2 = 0; s2 < 5; ++s2) { mtv[s2] = lds_tv[0][tid][s2]; mti[s2] = lds_ti[0][tid][s2]; }
#pragma unroll
        for (int w2 = 1; w2 < 4; ++w2)
#pragma unroll
            for (int s2 = 0; s2 < 5; ++s2) INS5(mtv, mti, lds_tv[w2][tid][s2], lds_ti[w2][tid][s2]);
        const int slot = js * N + row0 + tid;
        pout[slot] = dg;
        pout[4 * N + slot] = pt;
        pout[8 * N + slot] = ll;
        pout[12 * N + slot] = tt;
#pragma unroll
        for (int s2 = 0; s2 < 5; ++s2) {
            pout[16 * N + slot * 5 + s2] = mtv[s2];
            tixp[slot * 5 + s2] = mti[s2];
        }
    }
}

__global__ void k_final(const float* __restrict__ emb, const float* __restrict__ ws,
                        const int* __restrict__ tixp, float* __restrict__ out) {
    int row = blockIdx.x * 4 + (threadIdx.x >> 6);
    int lane = threadIdx.x & 63;
    const float* pdeg = ws + WS_PDEG;

    float dg = 0.f, pt = 0.f, ll = 0.f, tt = 0.f;
#pragma unroll
    for (int js = 0; js < 4; ++js) {
        int slot = js * N + row;
        dg += pdeg[slot]; pt += pdeg[4 * N + slot];
        ll += pdeg[8 * N + slot]; tt += pdeg[12 * N + slot];
    }

    float cd[20]; int ci[20];
#pragma unroll
    for (int js = 0; js < 4; ++js)
#pragma unroll
        for (int s = 0; s < 5; ++s) {
            int slot = js * N + row;
            cd[js * 5 + s] = pdeg[16 * N + slot * 5 + s];
            ci[js * 5 + s] = tixp[slot * 5 + s];
        }
    int nb[5];
    unsigned picked = 0;
#pragma unroll
    for (int sel = 0; sel < 5; ++sel) {
        float best = 1e31f; int bi = 0, bq = 0;
#pragma unroll
        for (int q = 0; q < 20; ++q) {
            bool ok = (((picked >> q) & 1u) == 0u) && (cd[q] < best);
            best = ok ? cd[q] : best;
            bi = ok ? ci[q] : bi;
            bq = ok ? q : bq;
        }
        picked |= (1u << bq);
        nb[sel] = bi;
    }

    float4 e = *(const float4*)(emb + (size_t)row * D + lane * 4);
    float4 gm = *(const float4*)(ws + WS_GMEAN + lane * 4);
    float gx = e.x - gm.x, gy = e.y - gm.y, gz = e.z - gm.z, gw = e.w - gm.w;
    float gd = gx * gx + gy * gy + gz * gz + gw * gw;
    float ax = 0.f, ay = 0.f, az = 0.f, aw = 0.f;
#pragma unroll
    for (int t = 0; t < 5; ++t) {
        float4 nv = *(const float4*)(emb + (size_t)nb[t] * D + lane * 4);
        ax += nv.x; ay += nv.y; az += nv.z; aw += nv.w;
    }
    ax *= 0.2f; ay *= 0.2f; az *= 0.2f; aw *= 0.2f;
    float lx = e.x - ax, ly = e.y - ay, lz = e.z - az, lw = e.w - aw;
    float ld = lx * lx + ly * ly + lz * lz + lw * lw;
#pragma unroll
    for (int mk = 32; mk >= 1; mk >>= 1) {
        gd += __shfl_xor(gd, mk);
        ld += __shfl_xor(ld, mk);
    }
    if (lane == 0) {
        float sqv = ws[WS_SQ + row];
        float mn = ws[WS_MAXN];
        float ent = logf(ll) - tt / ll;
        out[row] = sqv - pt / (dg + EPSF);
        out[N + row] = (dg > 0.f) ? ent : 0.f;
        out[2 * N + row] = 0.6f * sqrtf(gd) + 0.4f * sqrtf(ld);
        out[3 * N + row] = 0.5f * (dg / (8191.0f + EPSF)) + 0.5f * (sqrtf(sqv) / (mn + EPSF));
    }
}

extern "C" void kernel_launch(void* const* d_in, const int* in_sizes, int n_in,
                              void* d_out, int out_size, void* d_ws, size_t ws_size,
                              hipStream_t stream) {
    const float* emb = (const float*)d_in[0];
    const float* adj = (const float*)d_in[1];
    float* out = (float*)d_out;
    float* ws = (float*)d_ws;
    unsigned short* ebf = (unsigned short*)(ws + WS_EBF);

    hipMemsetAsync(ws + WS_MAXN, 0, 4, stream);
    k_prep<<<N / 4, 256, 0, stream>>>(emb, ws, ebf);
    k_colpart<<<256, 256, 0, stream>>>(emb, ws + WS_COLP);
    k_colred<<<1, 256, 0, stream>>>(ws + WS_COLP, ws + WS_GMEAN);
    k_main<<<1024, 256, 0, stream>>>(adj, ebf, ws, ws + WS_PDEG, (int*)(ws + WS_TIX));
    k_final<<<N / 4, 256, 0, stream>>>(emb, ws, (const int*)(ws + WS_TIX), out);
}